// Round 11
// baseline (448.733 us; speedup 1.0000x reference)
//
#include <hip/hip_runtime.h>

#define N_NODES 20000
#define N_EDGES 320000
#define F_DIM   128
#define H_DIM   256
#define M_ROWS  4096
#define NQ      2048
#define NIT     18
#define MM_ROWS 20032   // 313 * 64, padded row count for bf16 [x|msg]

typedef __attribute__((ext_vector_type(8))) short short8;   // 8 bf16 (4 VGPRs)
typedef __attribute__((ext_vector_type(4))) float f32x4;    // MFMA C/D

// ---------------- helpers ----------------

__device__ __forceinline__ float wred(float v) {
#pragma unroll
  for (int m = 32; m > 0; m >>= 1) v += __shfl_xor(v, m, 64);
  return v;
}

__device__ __forceinline__ float bred256(float v, float* lds) {
  v = wred(v);
  int w = threadIdx.x >> 6;
  if ((threadIdx.x & 63) == 0) lds[w] = v;
  __syncthreads();
  float tot = lds[0] + lds[1] + lds[2] + lds[3];
  __syncthreads();
  return tot;
}

__device__ __forceinline__ unsigned f2bf(float f) {
  unsigned u = __float_as_uint(f);
  unsigned r = u + 0x7fffu + ((u >> 16) & 1u);
  return r >> 16;
}
__device__ __forceinline__ float bflo(unsigned u) { return __uint_as_float(u << 16); }
__device__ __forceinline__ float bfhi(unsigned u) { return __uint_as_float(u & 0xffff0000u); }

// ---------------- k_init: deg histogram ∥ bf16 pack of x + Wtb ----------
#define DEG_BLKS ((N_EDGES + 255) / 256)    // 1250
#define PACK_X_BLKS (MM_ROWS * 16 / 256)    // 1252

__global__ __launch_bounds__(256) void k_init(const int* __restrict__ ei,
    int* __restrict__ deg, const float* __restrict__ x,
    const float* __restrict__ W10, const float* __restrict__ W11,
    unsigned* __restrict__ xu, unsigned* __restrict__ Wtb) {
  int bx = blockIdx.x;
  if (bx < DEG_BLKS) {
    int e = bx * 256 + threadIdx.x;
    if (e < N_EDGES) atomicAdd(&deg[ei[e]], 1);
  } else if (bx < DEG_BLKS + PACK_X_BLKS) {
    int gid = (bx - DEG_BLKS) * 256 + threadIdx.x;
    int row = gid >> 4;
    int q8 = gid & 15;
    uint4* xu4 = (uint4*)xu;
    if (row < N_NODES) {
      const float4* x4 = (const float4*)x;
      float4 a = x4[(size_t)row * 32 + q8 * 2];
      float4 b = x4[(size_t)row * 32 + q8 * 2 + 1];
      uint4 u;
      u.x = f2bf(a.x) | (f2bf(a.y) << 16);
      u.y = f2bf(a.z) | (f2bf(a.w) << 16);
      u.z = f2bf(b.x) | (f2bf(b.y) << 16);
      u.w = f2bf(b.z) | (f2bf(b.w) << 16);
      xu4[(size_t)row * 32 + q8] = u;
    } else {
      uint4 z = make_uint4(0, 0, 0, 0);
      xu4[(size_t)row * 32 + q8] = z;
      xu4[(size_t)row * 32 + 16 + q8] = z;
    }
  } else {
    int gid = (bx - DEG_BLKS - PACK_X_BLKS) * 256 + threadIdx.x;  // 0..32767
    int n = gid >> 7;
    int u = gid & 127;
    int k0 = u * 2;
    float v0 = (k0 < 128) ? W10[(size_t)k0 * H_DIM + n]
                          : W11[(size_t)(k0 - 128) * H_DIM + n];
    float v1 = (k0 + 1 < 128) ? W10[(size_t)(k0 + 1) * H_DIM + n]
                              : W11[(size_t)(k0 - 127) * H_DIM + n];
    Wtb[(size_t)n * 128 + u] = f2bf(v0) | (f2bf(v1) << 16);
  }
}

__global__ __launch_bounds__(1024) void k_scan(const int* __restrict__ deg,
    int* __restrict__ rowstart, float* __restrict__ dinv) {
  __shared__ int part[1024];
  int t = threadIdx.x;
  const int chunk = (N_NODES + 1023) / 1024;  // 20
  int lo = t * chunk;
  int hi = lo + chunk; if (hi > N_NODES) hi = N_NODES;
  int s = 0;
  for (int i = lo; i < hi; ++i) {
    int d = deg[i];
    dinv[i] = d > 0 ? rsqrtf((float)d) : 0.f;
    s += d;
  }
  part[t] = s;
  __syncthreads();
  for (int off = 1; off < 1024; off <<= 1) {
    int v = part[t];
    int add = (t >= off) ? part[t - off] : 0;
    __syncthreads();
    part[t] = v + add;
    __syncthreads();
  }
  int base = (t > 0) ? part[t - 1] : 0;
  for (int i = lo; i < hi; ++i) { rowstart[i] = base; base += deg[i]; }
  if (t == 0) rowstart[N_NODES] = part[1023];
}

// ---------------- k_build: CSR scatter ∥ bf16 A^T + b^T A ----------------
__global__ __launch_bounds__(256) void k_build(const int* __restrict__ ei,
    const int* __restrict__ rowstart, int* __restrict__ cursor,
    const float* __restrict__ dinv, int* __restrict__ cols, float* __restrict__ wvals,
    const float* __restrict__ A, const float* __restrict__ b,
    unsigned* __restrict__ Atu, float* __restrict__ btA_parts) {
  int bx = blockIdx.x;
  if (bx < DEG_BLKS) {
    int e = bx * 256 + threadIdx.x;
    if (e >= N_EDGES) return;
    int r = ei[e];
    int c = ei[N_EDGES + e];
    int pos = rowstart[r] + atomicAdd(&cursor[r], 1);
    cols[pos] = c;
    wvals[pos] = -dinv[r] * dinv[c];
  } else {
    int bp = bx - DEG_BLKS;          // 0..127
    int jp = (bp & 3) * 256 + threadIdx.x;   // 0..1023 col pairs
    int k0 = (bp >> 2) * 128;
    const float2* A2 = (const float2*)A;
    float acc0 = 0.f, acc1 = 0.f;
    for (int kk = 0; kk < 128; kk += 8) {
      float ax[8], ay[8];
#pragma unroll
      for (int i = 0; i < 8; ++i) {
        int k = k0 + kk + i;
        float2 a = A2[(size_t)k * 1024 + jp];
        float bk = b[k];
        acc0 += a.x * bk;
        acc1 += a.y * bk;
        ax[i] = a.x; ay[i] = a.y;
      }
      uint4 t0, t1;
      t0.x = f2bf(ax[0]) | (f2bf(ax[1]) << 16);
      t0.y = f2bf(ax[2]) | (f2bf(ax[3]) << 16);
      t0.z = f2bf(ax[4]) | (f2bf(ax[5]) << 16);
      t0.w = f2bf(ax[6]) | (f2bf(ax[7]) << 16);
      t1.x = f2bf(ay[0]) | (f2bf(ay[1]) << 16);
      t1.y = f2bf(ay[2]) | (f2bf(ay[3]) << 16);
      t1.z = f2bf(ay[4]) | (f2bf(ay[5]) << 16);
      t1.w = f2bf(ay[6]) | (f2bf(ay[7]) << 16);
      int uoff = (k0 + kk) >> 1;
      *(uint4*)(Atu + (size_t)(2 * jp) * 2048 + uoff) = t0;
      *(uint4*)(Atu + (size_t)(2 * jp + 1) * 2048 + uoff) = t1;
    }
    ((float2*)(btA_parts + (size_t)(bp >> 2) * NQ))[jp] = make_float2(acc0, acc1);
  }
}

// ---------------- k_mega: gram (blocks 0..255) ∥ msg1 (blocks 256+) ------
// Gram: G = A^T A (no diag), R8-proven form: 128x128 tile, 8 waves,
// in-block K-split between wave groups, 64 super-iters, 40 KB LDS.
// msg1: one wave per node row, gather bf16 x -> bf16 msg half.
#define GR_ST 20

__global__ __launch_bounds__(512) void k_mega(const unsigned* __restrict__ Atu,
    float* __restrict__ G, const int* __restrict__ rowstart,
    const int* __restrict__ cols, const float* __restrict__ wvals,
    unsigned* __restrict__ xu) {
  __shared__ unsigned shmem[10240];  // 40960 B (gram branch only)
  const int blk = blockIdx.x;
  if (blk >= 256) {
    // ---- msg1 branch: 8 waves, one row each ----
    int row = (blk - 256) * 8 + (threadIdx.x >> 6);
    int lane = threadIdx.x & 63;
    if (row >= N_NODES) return;
    int s0 = rowstart[row], s1 = rowstart[row + 1];
    float2 acc = make_float2(0.f, 0.f);
    for (int e = s0; e < s1; ++e) {
      int c = cols[e];
      float w = wvals[e];
      unsigned u = xu[(size_t)c * 128 + lane];
      acc.x += w * bflo(u);
      acc.y += w * bfhi(u);
    }
    xu[(size_t)row * 128 + 64 + lane] = f2bf(acc.x) | (f2bf(acc.y) << 16);
    return;
  }
  // ---- gram branch ----
  const int i0 = (blk >> 4) * 128, j0 = (blk & 15) * 128;
  const int tid = threadIdx.x;       // 0..511
  const int grp = tid >> 8;          // K-half within block
  const int t8 = tid & 255;
  const int w = tid >> 6;            // 0..7
  const int wt = w & 3;              // tile id
  const int lane = tid & 63;
  const int wr = (wt >> 1) * 64, wc = (wt & 1) * 64;
  const int srow = t8 >> 1, suo = (t8 & 1) * 8;
  const int frow = lane & 15, fqo = (lane >> 4) * 4;

  unsigned* shA = shmem + grp * 5120;
  unsigned* shB = shA + 2560;

  f32x4 acc[4][4];
#pragma unroll
  for (int a = 0; a < 4; ++a)
#pragma unroll
    for (int b = 0; b < 4; ++b) {
      acc[a][b][0] = 0.f; acc[a][b][1] = 0.f;
      acc[a][b][2] = 0.f; acc[a][b][3] = 0.f;
    }

  const unsigned* pa = Atu + (size_t)(i0 + srow) * 2048 + suo;
  const unsigned* pb = Atu + (size_t)(j0 + srow) * 2048 + suo;

  int ku = grp * 16;
  uint4 ra0 = *(const uint4*)(pa + ku);
  uint4 ra1 = *(const uint4*)(pa + ku + 4);
  uint4 rb0 = *(const uint4*)(pb + ku);
  uint4 rb1 = *(const uint4*)(pb + ku + 4);

  for (int si = 0; si < 64; ++si) {
    unsigned* as = shA + srow * GR_ST + suo;
    unsigned* bs = shB + srow * GR_ST + suo;
    *(uint4*)as = ra0; *(uint4*)(as + 4) = ra1;
    *(uint4*)bs = rb0; *(uint4*)(bs + 4) = rb1;
    if (si + 1 < 64) {
      ku = (si + 1) * 32 + grp * 16;
      ra0 = *(const uint4*)(pa + ku);
      ra1 = *(const uint4*)(pa + ku + 4);
      rb0 = *(const uint4*)(pb + ku);
      rb1 = *(const uint4*)(pb + ku + 4);
    }
    __syncthreads();
    short8 af[4], bf[4];
#pragma unroll
    for (int a = 0; a < 4; ++a)
      af[a] = *(const short8*)(shA + (wr + a * 16 + frow) * GR_ST + fqo);
#pragma unroll
    for (int b2 = 0; b2 < 4; ++b2)
      bf[b2] = *(const short8*)(shB + (wc + b2 * 16 + frow) * GR_ST + fqo);
#pragma unroll
    for (int a = 0; a < 4; ++a)
#pragma unroll
      for (int b2 = 0; b2 < 4; ++b2)
        acc[a][b2] = __builtin_amdgcn_mfma_f32_16x16x32_bf16(af[a], bf[b2], acc[a][b2], 0, 0, 0);
    __syncthreads();
  }

  const int q4 = lane >> 4, c16 = lane & 15;
  float* comb = (float*)shmem;
#pragma unroll
  for (int rnd = 0; rnd < 2; ++rnd) {
    if (grp == 1 && (wt >> 1) == rnd) {
      float* dst = comb + (wt & 1) * 4160;
#pragma unroll
      for (int a = 0; a < 4; ++a)
#pragma unroll
        for (int b2 = 0; b2 < 4; ++b2)
#pragma unroll
          for (int r = 0; r < 4; ++r)
            dst[(a * 16 + q4 * 4 + r) * 65 + b2 * 16 + c16] = acc[a][b2][r];
    }
    __syncthreads();
    if (grp == 0 && (wt >> 1) == rnd) {
      const float* src = comb + (wt & 1) * 4160;
#pragma unroll
      for (int a = 0; a < 4; ++a)
#pragma unroll
        for (int b2 = 0; b2 < 4; ++b2)
#pragma unroll
          for (int r = 0; r < 4; ++r)
            acc[a][b2][r] += src[(a * 16 + q4 * 4 + r) * 65 + b2 * 16 + c16];
    }
    __syncthreads();
  }

  if (grp == 0) {
#pragma unroll
    for (int a = 0; a < 4; ++a)
#pragma unroll
      for (int b2 = 0; b2 < 4; ++b2)
#pragma unroll
        for (int r = 0; r < 4; ++r) {
          int gr = i0 + wr + a * 16 + q4 * 4 + r;
          int gc = j0 + wc + b2 * 16 + c16;
          G[(size_t)gr * NQ + gc] = acc[a][b2][r];
        }
  }
}

// ---------------- GNN layer-1 GEMM via MFMA ----------------
#define WS_ST 20  // slice row stride in uints (16 data + 4 pad)

__global__ __launch_bounds__(256) void k_mm(const unsigned* __restrict__ xu,
    const unsigned* __restrict__ Wtb, const float* __restrict__ b1,
    const float* __restrict__ W20, const float* __restrict__ W21,
    float* __restrict__ t, float* __restrict__ s) {
  __shared__ unsigned Ws[2][256 * WS_ST];  // 2 x 20480 B
  const int row0 = blockIdx.x * 64;
  const int tid = threadIdx.x;
  const int w = tid >> 6, lane = tid & 63;
  const int colb = w * 64;
  const int frow = lane & 15, fqo = (lane >> 4) * 4;
  const int c16 = lane & 15, q4 = lane >> 4;

  f32x4 acc[4][4];
#pragma unroll
  for (int a = 0; a < 4; ++a)
#pragma unroll
    for (int b = 0; b < 4; ++b) {
      acc[a][b][0] = 0.f; acc[a][b][1] = 0.f;
      acc[a][b][2] = 0.f; acc[a][b][3] = 0.f;
    }

  const uint4* Wtb4 = (const uint4*)Wtb;
  uint4 rw[4];
#pragma unroll
  for (int j = 0; j < 4; ++j) rw[j] = Wtb4[(size_t)tid * 32 + j];

  for (int kc = 0; kc < 8; ++kc) {
    const int b = kc & 1;
    unsigned* dst = Ws[b] + tid * WS_ST;
#pragma unroll
    for (int j = 0; j < 4; ++j) *(uint4*)(dst + j * 4) = rw[j];
    if (kc + 1 < 8) {
#pragma unroll
      for (int j = 0; j < 4; ++j) rw[j] = Wtb4[(size_t)tid * 32 + (kc + 1) * 4 + j];
    }
    __syncthreads();
    short8 af[4], bf[4];
#pragma unroll
    for (int a = 0; a < 4; ++a)
      af[a] = *(const short8*)(xu + (size_t)(row0 + a * 16 + frow) * 128 + kc * 16 + fqo);
#pragma unroll
    for (int n = 0; n < 4; ++n)
      bf[n] = *(const short8*)(Ws[b] + (colb + n * 16 + frow) * WS_ST + fqo);
#pragma unroll
    for (int a = 0; a < 4; ++a)
#pragma unroll
      for (int n = 0; n < 4; ++n)
        acc[a][n] = __builtin_amdgcn_mfma_f32_16x16x32_bf16(af[a], bf[n], acc[a][n], 0, 0, 0);
    __syncthreads();
  }

  float tp[4][4] = {}, sp[4][4] = {};
#pragma unroll
  for (int b2 = 0; b2 < 4; ++b2) {
    int gc = colb + b2 * 16 + c16;
    float w20 = W20[gc], w21 = W21[gc], bb = b1[gc];
#pragma unroll
    for (int a = 0; a < 4; ++a)
#pragma unroll
      for (int r = 0; r < 4; ++r) {
        float val = acc[a][b2][r] + bb;
        val = val > 0.f ? val : 0.f;
        tp[a][r] += val * w20;
        sp[a][r] += val * w21;
      }
  }
#pragma unroll
  for (int a = 0; a < 4; ++a)
#pragma unroll
    for (int r = 0; r < 4; ++r) {
#pragma unroll
      for (int m = 1; m < 16; m <<= 1) {
        tp[a][r] += __shfl_xor(tp[a][r], m, 64);
        sp[a][r] += __shfl_xor(sp[a][r], m, 64);
      }
    }
  if (c16 == 0) {
#pragma unroll
    for (int a = 0; a < 4; ++a)
#pragma unroll
      for (int r = 0; r < 4; ++r) {
        int gr = row0 + a * 16 + q4 * 4 + r;
        if (gr < N_NODES) {
          atomicAdd(&t[gr], tp[a][r]);
          atomicAdd(&s[gr], sp[a][r]);
        }
      }
  }
}

// ---------------- GNN layer 2 scalar gather ----------------

__global__ __launch_bounds__(256) void k_h2(const float* __restrict__ t,
    const float* __restrict__ s, const int* __restrict__ rowstart,
    const int* __restrict__ cols, const float* __restrict__ wvals,
    const float* __restrict__ lamb, const float* __restrict__ b2, float* __restrict__ h2) {
  int i = blockIdx.x * 256 + threadIdx.x;
  if (i >= N_NODES) return;
  float m = 0.f;
  int s0 = rowstart[i], s1 = rowstart[i + 1];
  for (int e = s0; e < s1; ++e) m += wvals[e] * s[cols[e]];
  float val = t[i] + m + b2[0];
  val = val > 0.f ? val : 0.f;
  h2[i] = lamb[0] * val;
}

// ---------------- k_gq: rhs + q + fp32 G -> bf16 Gb + qcorr --------------
// block = row (2048 blocks). Wave-0 computes bta sum + hf + r0[row];
// all threads then convert the G row with diag(hf) folded in.
__global__ __launch_bounds__(256) void k_gq(const float* __restrict__ G,
    const float* __restrict__ h2, const int* __restrict__ fids,
    const float* __restrict__ xprior, const float* __restrict__ btA_parts,
    unsigned* __restrict__ Gb, float* __restrict__ qcorr, float* __restrict__ r0) {
  __shared__ float hfs;
  const int row = blockIdx.x, tid = threadIdx.x;
  if (tid < 32) {
    float bta = btA_parts[(size_t)tid * NQ + row];
#pragma unroll
    for (int m = 16; m > 0; m >>= 1) bta += __shfl_xor(bta, m, 64);
    if (tid == 0) {
      float hf = h2[fids[row]] + 1e-5f;
      hfs = hf;
      r0[row] = xprior[row] * hf + bta;
    }
  }
  __syncthreads();
  float hf = hfs;
  const float4* g4 = (const float4*)(G + (size_t)row * NQ);
  float4 a0 = g4[tid * 2], b0 = g4[tid * 2 + 1];
  float v[8] = {a0.x, a0.y, a0.z, a0.w, b0.x, b0.y, b0.z, b0.w};
  bool diag = ((row >> 3) == tid);
  if (diag) v[row & 7] += hf;
  uint4 u;
  u.x = f2bf(v[0]) | (f2bf(v[1]) << 16);
  u.y = f2bf(v[2]) | (f2bf(v[3]) << 16);
  u.z = f2bf(v[4]) | (f2bf(v[5]) << 16);
  u.w = f2bf(v[6]) | (f2bf(v[7]) << 16);
  ((uint4*)(Gb + (size_t)row * 1024))[tid] = u;
  if (diag) {
    float vd = v[row & 7];
    qcorr[row] = vd - __uint_as_float(f2bf(vd) << 16);
  }
}

// ---------------- CG: ONE kernel/iter.  Qp = Gb p + qcorr*p --------------
__global__ __launch_bounds__(256) void k_cgG(int k, const unsigned* __restrict__ Gb,
    const float* __restrict__ qcorr,
    const float* __restrict__ r_old, float* __restrict__ r_new,
    const float* __restrict__ p_old, float* __restrict__ p_new,
    const float* __restrict__ Qp_in, float* __restrict__ Qp_out,
    float* __restrict__ xcg) {
  __shared__ float pshare[NQ];
  __shared__ float lds[4];
  const int tid = threadIdx.x, bid = blockIdx.x;
  const float4* r4 = (const float4*)r_old;
  float4 ra = r4[tid * 2], rb2 = r4[tid * 2 + 1];
  float pv[8];
  if (k == 0) {
    pv[0] = ra.x; pv[1] = ra.y; pv[2] = ra.z; pv[3] = ra.w;
    pv[4] = rb2.x; pv[5] = rb2.y; pv[6] = rb2.z; pv[7] = rb2.w;
    if (bid == 0) {
      ((float4*)p_new)[tid * 2] = ra;
      ((float4*)p_new)[tid * 2 + 1] = rb2;
    }
  } else {
    const float4* p4 = (const float4*)p_old;
    const float4* qp4 = (const float4*)Qp_in;
    float4 pa = p4[tid * 2], pb = p4[tid * 2 + 1];
    float4 qa = qp4[tid * 2], qb = qp4[tid * 2 + 1];
    float rr = ra.x * ra.x + ra.y * ra.y + ra.z * ra.z + ra.w * ra.w +
               rb2.x * rb2.x + rb2.y * rb2.y + rb2.z * rb2.z + rb2.w * rb2.w;
    float pap = pa.x * qa.x + pa.y * qa.y + pa.z * qa.z + pa.w * qa.w +
                pb.x * qb.x + pb.y * qb.y + pb.z * qb.z + pb.w * qb.w;
    rr = bred256(rr, lds);
    pap = bred256(pap, lds);
    float alpha = rr / pap;
    if (bid == 0) {
      float4* x4 = (float4*)xcg;
      float4 xa = x4[tid * 2], xb = x4[tid * 2 + 1];
      xa.x += alpha * pa.x; xa.y += alpha * pa.y;
      xa.z += alpha * pa.z; xa.w += alpha * pa.w;
      xb.x += alpha * pb.x; xb.y += alpha * pb.y;
      xb.z += alpha * pb.z; xb.w += alpha * pb.w;
      x4[tid * 2] = xa; x4[tid * 2 + 1] = xb;
    }
    ra.x -= alpha * qa.x; ra.y -= alpha * qa.y;
    ra.z -= alpha * qa.z; ra.w -= alpha * qa.w;
    rb2.x -= alpha * qb.x; rb2.y -= alpha * qb.y;
    rb2.z -= alpha * qb.z; rb2.w -= alpha * qb.w;
    float rrn = ra.x * ra.x + ra.y * ra.y + ra.z * ra.z + ra.w * ra.w +
                rb2.x * rb2.x + rb2.y * rb2.y + rb2.z * rb2.z + rb2.w * rb2.w;
    rrn = bred256(rrn, lds);
    float beta = rrn / rr;
    pv[0] = ra.x + beta * pa.x; pv[1] = ra.y + beta * pa.y;
    pv[2] = ra.z + beta * pa.z; pv[3] = ra.w + beta * pa.w;
    pv[4] = rb2.x + beta * pb.x; pv[5] = rb2.y + beta * pb.y;
    pv[6] = rb2.z + beta * pb.z; pv[7] = rb2.w + beta * pb.w;
    if (bid == 0) {
      ((float4*)r_new)[tid * 2] = ra;
      ((float4*)r_new)[tid * 2 + 1] = rb2;
      ((float4*)p_new)[tid * 2] = make_float4(pv[0], pv[1], pv[2], pv[3]);
      ((float4*)p_new)[tid * 2 + 1] = make_float4(pv[4], pv[5], pv[6], pv[7]);
    }
  }
  ((float4*)pshare)[tid * 2] = make_float4(pv[0], pv[1], pv[2], pv[3]);
  ((float4*)pshare)[tid * 2 + 1] = make_float4(pv[4], pv[5], pv[6], pv[7]);
  __syncthreads();
  const int w = tid >> 6, lane = tid & 63;
  const int row = bid * 4 + w;
  const uint4* Gr = (const uint4*)(Gb + (size_t)row * 1024);
  const float4* ps4 = (const float4*)pshare;
  float acc = 0.f;
#pragma unroll
  for (int c = 0; c < 4; ++c) {
    uint4 gv = Gr[c * 64 + lane];
    float4 pa = ps4[c * 128 + lane * 2];
    float4 pb = ps4[c * 128 + lane * 2 + 1];
    acc += bflo(gv.x) * pa.x + bfhi(gv.x) * pa.y;
    acc += bflo(gv.y) * pa.z + bfhi(gv.y) * pa.w;
    acc += bflo(gv.z) * pb.x + bfhi(gv.z) * pb.y;
    acc += bflo(gv.w) * pb.z + bfhi(gv.w) * pb.w;
  }
  acc = wred(acc);
  if (lane == 0) Qp_out[row] = acc + qcorr[row] * pshare[row];
}

// ---------------- final: alpha + out = x + alpha p -----------------------
__global__ __launch_bounds__(256) void k_cgfin(const float* __restrict__ r_last,
    const float* __restrict__ p_last, const float* __restrict__ Qp,
    const float* __restrict__ xcg, float* __restrict__ out) {
  const int tid = threadIdx.x;
  const int lane = tid & 63;
  const float4* r4 = (const float4*)r_last;
  const float4* p4 = (const float4*)p_last;
  const float4* q4 = (const float4*)Qp;
  float rr = 0.f, pap = 0.f;
#pragma unroll
  for (int c = 0; c < 4; ++c) {
#pragma unroll
    for (int hh = 0; hh < 2; ++hh) {
      float4 rv = r4[c * 128 + lane * 2 + hh];
      float4 pv = p4[c * 128 + lane * 2 + hh];
      float4 qv = q4[c * 128 + lane * 2 + hh];
      rr += rv.x * rv.x + rv.y * rv.y + rv.z * rv.z + rv.w * rv.w;
      pap += pv.x * qv.x + pv.y * qv.y + pv.z * qv.z + pv.w * qv.w;
    }
  }
  rr = wred(rr);
  pap = wred(pap);
  float alpha = rr / pap;
  const float4* x4 = (const float4*)xcg;
  float4* o4 = (float4*)out;
#pragma unroll
  for (int hh = 0; hh < 2; ++hh) {
    int i4 = tid * 2 + hh;
    float4 xv = x4[i4];
    float4 pv = p4[i4];
    xv.x += alpha * pv.x; xv.y += alpha * pv.y;
    xv.z += alpha * pv.z; xv.w += alpha * pv.w;
    o4[i4] = xv;
  }
}

// ---------------- launch ----------------

extern "C" void kernel_launch(void* const* d_in, const int* in_sizes, int n_in,
                              void* d_out, int out_size, void* d_ws, size_t ws_size,
                              hipStream_t stream) {
  const float* x      = (const float*)d_in[0];
  const int*   ei     = (const int*)d_in[1];
  const float* A      = (const float*)d_in[2];
  const float* b      = (const float*)d_in[3];
  const int*   fids   = (const int*)d_in[4];
  const float* xprior = (const float*)d_in[5];
  const float* lamb   = (const float*)d_in[6];
  const float* W10    = (const float*)d_in[7];
  const float* W11    = (const float*)d_in[8];
  const float* b1     = (const float*)d_in[9];
  const float* W20    = (const float*)d_in[10];
  const float* W21    = (const float*)d_in[11];
  const float* b2     = (const float*)d_in[12];
  float* out = (float*)d_out;

  char* base = (char*)d_ws;
  size_t o = 0;
  auto alloc = [&](size_t bytes) { size_t r = o; o = (o + bytes + 255) & ~size_t(255); return r; };

  // zero-init region (deg, cursor, xcg, t, s)
  size_t off_deg    = alloc(N_NODES * 4);
  size_t off_cursor = alloc(N_NODES * 4);
  size_t off_xcg    = alloc(NQ * 4);
  size_t off_t      = alloc(N_NODES * 4);
  size_t off_s      = alloc(N_NODES * 4);
  size_t zero_end   = o;
  size_t off_rowst  = alloc((N_NODES + 1) * 4);
  size_t off_dinv   = alloc(N_NODES * 4);
  size_t off_h2     = alloc(N_NODES * 4);
  size_t off_r0     = alloc(NQ * 4);
  size_t off_r1     = alloc(NQ * 4);
  size_t off_p0     = alloc(NQ * 4);
  size_t off_p1     = alloc(NQ * 4);
  size_t off_Qp0    = alloc(NQ * 4);
  size_t off_Qp1    = alloc(NQ * 4);
  size_t off_qcorr  = alloc(NQ * 4);
  size_t off_btAp   = alloc(32 * NQ * 4);
  size_t off_Wtb    = alloc(256 * 128 * 4);
  // GNN region {cols, wvals, xmsgb}; Gb reuses it after k_h2/k_mm complete
  size_t sz_cols  = (size_t)N_EDGES * 4 + 256;
  size_t sz_wvals = (size_t)N_EDGES * 4 + 256;
  size_t sz_xmsg  = (size_t)MM_ROWS * 256 * 2;
  size_t off_gnn  = alloc(sz_cols + sz_wvals + sz_xmsg);
  size_t off_Atu  = alloc((size_t)M_ROWS * NQ * 2);   // separate: gram ∥ msg1
  size_t off_G    = alloc((size_t)NQ * NQ * 4);
  if (o > ws_size) return;

  int*   deg      = (int*)(base + off_deg);
  int*   cursor   = (int*)(base + off_cursor);
  float* xcg      = (float*)(base + off_xcg);
  float* t        = (float*)(base + off_t);
  float* s        = (float*)(base + off_s);
  int*   rowstart = (int*)(base + off_rowst);
  float* dinv     = (float*)(base + off_dinv);
  float* h2       = (float*)(base + off_h2);
  float* rb[2]    = {(float*)(base + off_r0), (float*)(base + off_r1)};
  float* pg[2]    = {(float*)(base + off_p0), (float*)(base + off_p1)};
  float* Qpb[2]   = {(float*)(base + off_Qp0), (float*)(base + off_Qp1)};
  float* qcorr    = (float*)(base + off_qcorr);
  float* btA_parts = (float*)(base + off_btAp);
  unsigned* Wtb   = (unsigned*)(base + off_Wtb);
  int*   cols     = (int*)(base + off_gnn);
  float* wvals    = (float*)(base + off_gnn + sz_cols);
  unsigned* xmsgb = (unsigned*)(base + off_gnn + sz_cols + sz_wvals);
  unsigned* Gb    = (unsigned*)(base + off_gnn);   // reuse after h2/mm done
  unsigned* Atu   = (unsigned*)(base + off_Atu);
  float* G        = (float*)(base + off_G);

  hipMemsetAsync(d_ws, 0, zero_end, stream);

  // deg ∥ bf16 pack (x half + Wtb)
  k_init<<<DEG_BLKS + PACK_X_BLKS + 128, 256, 0, stream>>>(ei, deg, x, W10, W11, xmsgb, Wtb);
  k_scan<<<1, 1024, 0, stream>>>(deg, rowstart, dinv);
  // CSR scatter ∥ bf16 A^T + b^T A
  k_build<<<DEG_BLKS + 128, 256, 0, stream>>>(ei, rowstart, cursor, dinv, cols, wvals,
                                              A, b, Atu, btA_parts);
  // gram ∥ msg1 (co-scheduled)
  k_mega<<<256 + (N_NODES + 7) / 8, 512, 0, stream>>>(Atu, G, rowstart, cols, wvals, xmsgb);
  // GNN layer-1 GEMM + layer-2 gather
  k_mm<<<MM_ROWS / 64, 256, 0, stream>>>(xmsgb, Wtb, b1, W20, W21, t, s);
  k_h2<<<(N_NODES + 255) / 256, 256, 0, stream>>>(t, s, rowstart, cols, wvals, lamb, b2, h2);
  // rhs + bf16 G + qcorr (Gb overwrites GNN region — dead after h2/mm)
  k_gq<<<NQ, 256, 0, stream>>>(G, h2, fids, xprior, btA_parts, Gb, qcorr, rb[0]);

  // CG: 1 kernel/iter
  k_cgG<<<512, 256, 0, stream>>>(0, Gb, qcorr, rb[0], rb[0], pg[0], pg[0],
                                 Qpb[1], Qpb[0], xcg);
  for (int k = 1; k < NIT; ++k) {
    k_cgG<<<512, 256, 0, stream>>>(k, Gb, qcorr, rb[(k - 1) & 1], rb[k & 1],
                                   pg[(k - 1) & 1], pg[k & 1],
                                   Qpb[(k - 1) & 1], Qpb[k & 1], xcg);
  }
  k_cgfin<<<1, 256, 0, stream>>>(rb[(NIT - 1) & 1], pg[(NIT - 1) & 1],
                                 Qpb[(NIT - 1) & 1], xcg, out);
}